// Round 4
// baseline (390.007 us; speedup 1.0000x reference)
//
#include <hip/hip_runtime.h>
#include <hip/hip_bf16.h>

// Performer (FAVOR+) attention, bf16-MFMA fused two-pass. v4:
// v3 (grid 1024, direct global->A-frag loads, paired-row V^T stores,
// launch_bounds(256,3)) + z race fix: per-wave z partial slots instead of
// zeroed LDS atomics (v3's zero->atomicAdd had no barrier between them).

#define BH 32
#define LL 8192
#define DD 64
#define MM 256
#define NRM 0.35355339059327373f   // 64^-0.25
#define SQS 0.0625f                // 0.5*NRM^2
#define EPSK 1e-6f
#define EPSZ 1e-6f

#define NCHUNK 32                  // chunks per bh -> grid 1024
#define CROWS (LL / NCHUNK)        // 256 rows per block
#define NTILE (CROWS / 32)         // 8 tiles of 32 rows

typedef __attribute__((ext_vector_type(8))) short bf16x8;
typedef __attribute__((ext_vector_type(4))) float f32x4;
#define MFMA(a, b, c) __builtin_amdgcn_mfma_f32_16x16x32_bf16(a, b, c, 0, 0, 0)

static __device__ __forceinline__ short f2bf(float x) {
    union { float f; unsigned u; } c{x};
    unsigned r = c.u + 0x7fffu + ((c.u >> 16) & 1u);   // RNE
    return (short)(r >> 16);
}

// P as MFMA B-operand fragments (NRM folded): pb[ks][mt],
// element jj = P[64*wv + mt*16 + (lane&15)][ks*32 + quad*8 + jj] * NRM
static __device__ __forceinline__ void load_pfrags(
    const float* __restrict__ Pm, int wv, int quad, int l16, bf16x8 pb[2][4])
{
#pragma unroll
    for (int ks = 0; ks < 2; ++ks)
#pragma unroll
        for (int mt = 0; mt < 4; ++mt) {
            const float* pr = Pm + (wv * 64 + mt * 16 + l16) * DD + ks * 32 + quad * 8;
            float4 p0 = *(const float4*)pr;
            float4 p1 = *(const float4*)(pr + 4);
            bf16x8 f;
            f[0] = f2bf(p0.x * NRM); f[1] = f2bf(p0.y * NRM);
            f[2] = f2bf(p0.z * NRM); f[3] = f2bf(p0.w * NRM);
            f[4] = f2bf(p1.x * NRM); f[5] = f2bf(p1.y * NRM);
            f[6] = f2bf(p1.z * NRM); f[7] = f2bf(p1.w * NRM);
            pb[ks][mt] = f;
        }
}

// Direct global->A-frag load of a 32-row tile of X (fp32 [l][64]) + row cl.
// af[lt][ks] = bf16 A-operand; cuse[lt][r] = EPSK - SQS*|row|^2 for C-layout
// row quad*4+r of subtile lt.
static __device__ __forceinline__ void load_afrags(
    const float* __restrict__ xb, int row0, int quad, int l16,
    bf16x8 af[2][2], float cuse[2][4])
{
#pragma unroll
    for (int lt = 0; lt < 2; ++lt) {
        const float* pr = xb + (size_t)(row0 + lt * 16 + l16) * DD + quad * 8;
        float4 f0 = *(const float4*)pr;
        float4 f1 = *(const float4*)(pr + 4);
        float4 f2 = *(const float4*)(pr + 32);
        float4 f3 = *(const float4*)(pr + 36);
        float sq = f0.x*f0.x + f0.y*f0.y + f0.z*f0.z + f0.w*f0.w
                 + f1.x*f1.x + f1.y*f1.y + f1.z*f1.z + f1.w*f1.w
                 + f2.x*f2.x + f2.y*f2.y + f2.z*f2.z + f2.w*f2.w
                 + f3.x*f3.x + f3.y*f3.y + f3.z*f3.z + f3.w*f3.w;
        sq += __shfl_xor(sq, 16);
        sq += __shfl_xor(sq, 32);
        const float cl = EPSK - SQS * sq;      // all lanes of row l16
#pragma unroll
        for (int r = 0; r < 4; ++r) cuse[lt][r] = __shfl(cl, quad * 4 + r);
        bf16x8 a0, a1;
        a0[0]=f2bf(f0.x); a0[1]=f2bf(f0.y); a0[2]=f2bf(f0.z); a0[3]=f2bf(f0.w);
        a0[4]=f2bf(f1.x); a0[5]=f2bf(f1.y); a0[6]=f2bf(f1.z); a0[7]=f2bf(f1.w);
        a1[0]=f2bf(f2.x); a1[1]=f2bf(f2.y); a1[2]=f2bf(f2.z); a1[3]=f2bf(f2.w);
        a1[4]=f2bf(f3.x); a1[5]=f2bf(f3.y); a1[6]=f2bf(f3.z); a1[7]=f2bf(f3.w);
        af[lt][0] = a0; af[lt][1] = a1;
    }
}

// ---------------- Kernel A: kv += K'^T V, ksum += colsum(K') ----------------
__global__ __launch_bounds__(256, 3) void kv_kernel(
    const float* __restrict__ kin, const float* __restrict__ vin,
    const float* __restrict__ Pm, float* __restrict__ kv, float* __restrict__ ksum)
{
    __shared__ short Vt[64 * 40];    // V^T tile  [d][l], stride 40 shorts
    __shared__ short Ktp[256 * 40];  // K'^T tile [m][l], stride 40

    const int t = threadIdx.x;
    const int lane = t & 63, wv = t >> 6;
    const int quad = lane >> 4, l16 = lane & 15;
    const int bh = blockIdx.x >> 5, chunk = blockIdx.x & 31;

    bf16x8 pb[2][4];
    load_pfrags(Pm, wv, quad, l16, pb);

    f32x4 kvacc[4][4];
#pragma unroll
    for (int mt = 0; mt < 4; ++mt)
#pragma unroll
        for (int dt = 0; dt < 4; ++dt) kvacc[mt][dt] = (f32x4)0.f;
    float ksacc[4] = {0.f, 0.f, 0.f, 0.f};

    const size_t base = ((size_t)bh * LL + (size_t)chunk * CROWS) * DD;
    const float* kb = kin + base;
    const float* vb = vin + base;
    const int lp = t >> 4, sd4 = t & 15;   // V staging: rows 2lp,2lp+1 cols sd4*4..+3

    for (int tile = 0; tile < NTILE; ++tile) {
        // --- global loads (pre-sync, independent of LDS state) ---
        const int gi = (tile * 32 + 2 * lp) * DD + sd4 * 4;
        float4 vf0 = *(const float4*)(vb + gi);
        float4 vf1 = *(const float4*)(vb + gi + DD);
        bf16x8 Ka[2][2]; float cuse[2][4];
        load_afrags(kb, tile * 32, quad, l16, Ka, cuse);

        __syncthreads();             // prev-iter MFMA reads of Vt/Ktp done
        // --- V^T stores: dword (two adjacent l) per bank word ---
#pragma unroll
        for (int c = 0; c < 4; ++c) {
            union { short s[2]; unsigned u; } p;
            p.s[0] = f2bf((&vf0.x)[c]);
            p.s[1] = f2bf((&vf1.x)[c]);
            *(unsigned*)&Vt[(sd4 * 4 + c) * 40 + 2 * lp] = p.u;
        }
        // --- proj MFMA (register A-frags, no LDS) ---
        f32x4 pt[2][4];
#pragma unroll
        for (int lt = 0; lt < 2; ++lt)
#pragma unroll
            for (int mt = 0; mt < 4; ++mt) pt[lt][mt] = (f32x4)0.f;
#pragma unroll
        for (int ks = 0; ks < 2; ++ks)
#pragma unroll
            for (int lt = 0; lt < 2; ++lt)
#pragma unroll
                for (int mt = 0; mt < 4; ++mt)
                    pt[lt][mt] = MFMA(Ka[lt][ks], pb[ks][mt], pt[lt][mt]);
        // --- exp -> K', ksum, K'^T[m][l] (b64 l-contig writes) ---
#pragma unroll
        for (int lt = 0; lt < 2; ++lt)
#pragma unroll
            for (int mt = 0; mt < 4; ++mt) {
                union { short s[4]; unsigned long long u; } uo;
#pragma unroll
                for (int r = 0; r < 4; ++r) {
                    float w = __expf(pt[lt][mt][r] + cuse[lt][r]);
                    ksacc[mt] += w;
                    uo.s[r] = f2bf(w);
                }
                *(unsigned long long*)&Ktp[(wv * 64 + mt * 16 + l16) * 40 + lt * 16 + quad * 4] = uo.u;
            }
        __syncthreads();
        // --- kv MFMA: kv[m][d] += K'^T[m][l] V[l][d], K=32 = one step ---
        bf16x8 aK[4], bV[4];
#pragma unroll
        for (int mt = 0; mt < 4; ++mt)
            aK[mt] = *(bf16x8*)&Ktp[(wv * 64 + mt * 16 + l16) * 40 + quad * 8];
#pragma unroll
        for (int dt = 0; dt < 4; ++dt)
            bV[dt] = *(bf16x8*)&Vt[(dt * 16 + l16) * 40 + quad * 8];
#pragma unroll
        for (int mt = 0; mt < 4; ++mt)
#pragma unroll
            for (int dt = 0; dt < 4; ++dt)
                kvacc[mt][dt] = MFMA(aK[mt], bV[dt], kvacc[mt][dt]);
    }
    // --- epilogue: atomics into workspace ---
    float* kvg = kv + (size_t)bh * MM * DD;
#pragma unroll
    for (int mt = 0; mt < 4; ++mt) {
        float r = ksacc[mt];
        r += __shfl_xor(r, 16); r += __shfl_xor(r, 32);
        if (quad == 0) atomicAdd(ksum + bh * MM + wv * 64 + mt * 16 + l16, r);
#pragma unroll
        for (int dt = 0; dt < 4; ++dt)
#pragma unroll
            for (int rg = 0; rg < 4; ++rg)
                atomicAdd(kvg + (wv * 64 + mt * 16 + quad * 4 + rg) * DD + dt * 16 + l16,
                          kvacc[mt][dt][rg]);
    }
}

// ---------------- Kernel B: out = (Q' kv) * z ------------------------------
__global__ __launch_bounds__(256, 3) void out_kernel(
    const float* __restrict__ qin, const float* __restrict__ Pm,
    const float* __restrict__ kv, const float* __restrict__ ksum,
    float* __restrict__ out)
{
    __shared__ short Qp[32 * 264];    // Q' tile bf16 [l][m], stride 264
    __shared__ short kvT[64 * 264];   // kv^T bf16 [d][m]
    __shared__ float ks_lds[MM];
    __shared__ float z_lds[4 * 32];   // per-wave z partials [wv][row] — no atomics

    const int t = threadIdx.x;
    const int lane = t & 63, wv = t >> 6;
    const int quad = lane >> 4, l16 = lane & 15;
    const int bh = blockIdx.x >> 5, chunk = blockIdx.x & 31;

    bf16x8 pb[2][4];
    load_pfrags(Pm, wv, quad, l16, pb);

    // --- stage kv^T (bf16 transposed) + ksum, once per block ---
    const float* kvg = kv + (size_t)bh * MM * DD;
#pragma unroll
    for (int it = 0; it < 16; ++it) {
        int i = t + it * 256;          // float4 index over [256][16]
        int m = i >> 4, d4 = i & 15;
        float4 f = *(const float4*)(kvg + m * DD + d4 * 4);
        kvT[(d4 * 4 + 0) * 264 + m] = f2bf(f.x);
        kvT[(d4 * 4 + 1) * 264 + m] = f2bf(f.y);
        kvT[(d4 * 4 + 2) * 264 + m] = f2bf(f.z);
        kvT[(d4 * 4 + 3) * 264 + m] = f2bf(f.w);
    }
    ks_lds[t] = ksum[bh * MM + t];
    __syncthreads();
    float ksv[4];
#pragma unroll
    for (int mt = 0; mt < 4; ++mt) ksv[mt] = ks_lds[wv * 64 + mt * 16 + l16];

    const size_t base = ((size_t)bh * LL + (size_t)chunk * CROWS) * DD;
    const float* qb = qin + base;
    float* ob = out + base;

    for (int tile = 0; tile < NTILE; ++tile) {
        bf16x8 Qa[2][2]; float cuse[2][4];
        load_afrags(qb, tile * 32, quad, l16, Qa, cuse);

        __syncthreads();             // prev-iter Qp/z_lds readers done
        // --- proj MFMA ---
        f32x4 pt[2][4];
#pragma unroll
        for (int lt = 0; lt < 2; ++lt)
#pragma unroll
            for (int mt = 0; mt < 4; ++mt) pt[lt][mt] = (f32x4)0.f;
#pragma unroll
        for (int ks = 0; ks < 2; ++ks)
#pragma unroll
            for (int lt = 0; lt < 2; ++lt)
#pragma unroll
                for (int mt = 0; mt < 4; ++mt)
                    pt[lt][mt] = MFMA(Qa[lt][ks], pb[ks][mt], pt[lt][mt]);
        // --- exp -> Q' LDS [l][m], z partials in regs ---
        float zp[2][4] = {{0.f,0.f,0.f,0.f},{0.f,0.f,0.f,0.f}};
#pragma unroll
        for (int lt = 0; lt < 2; ++lt)
#pragma unroll
            for (int mt = 0; mt < 4; ++mt)
#pragma unroll
                for (int r = 0; r < 4; ++r) {
                    float w = __expf(pt[lt][mt][r] + cuse[lt][r]);
                    zp[lt][r] += w * ksv[mt];
                    Qp[(lt * 16 + quad * 4 + r) * 264 + wv * 64 + mt * 16 + l16] = f2bf(w);
                }
        // z: reduce over 16 m-lanes; each wave writes its private slot
#pragma unroll
        for (int lt = 0; lt < 2; ++lt)
#pragma unroll
            for (int r = 0; r < 4; ++r) {
                float vz = zp[lt][r];
                vz += __shfl_xor(vz, 1); vz += __shfl_xor(vz, 2);
                vz += __shfl_xor(vz, 4); vz += __shfl_xor(vz, 8);
                if (l16 == 0) z_lds[wv * 32 + lt * 16 + quad * 4 + r] = vz;
            }
        __syncthreads();
        // --- out MFMA: wave wv owns d-tile wv; K = 256 -> 8 steps ---
        f32x4 oc[2];
        oc[0] = (f32x4)0.f; oc[1] = (f32x4)0.f;
#pragma unroll
        for (int ks = 0; ks < 8; ++ks) {
            bf16x8 bk = *(bf16x8*)&kvT[(wv * 16 + l16) * 264 + ks * 32 + quad * 8];
#pragma unroll
            for (int lt = 0; lt < 2; ++lt) {
                bf16x8 aq = *(bf16x8*)&Qp[(lt * 16 + l16) * 264 + ks * 32 + quad * 8];
                oc[lt] = MFMA(aq, bk, oc[lt]);
            }
        }
#pragma unroll
        for (int lt = 0; lt < 2; ++lt)
#pragma unroll
            for (int r = 0; r < 4; ++r) {
                const int row = lt * 16 + quad * 4 + r;
                const float zr = z_lds[row] + z_lds[32 + row]
                               + z_lds[64 + row] + z_lds[96 + row];
                const float z = 1.f / (zr + EPSZ);
                ob[(size_t)(tile * 32 + row) * DD + wv * 16 + l16] = oc[lt][r] * z;
            }
    }
}

extern "C" void kernel_launch(void* const* d_in, const int* in_sizes, int n_in,
                              void* d_out, int out_size, void* d_ws, size_t ws_size,
                              hipStream_t stream) {
    const float* q  = (const float*)d_in[0];
    const float* k  = (const float*)d_in[1];
    const float* v  = (const float*)d_in[2];
    const float* Pm = (const float*)d_in[3];

    float* kvw = (float*)d_ws;                       // [BH, M, D]
    float* ksw = kvw + (size_t)BH * MM * DD;         // [BH, M]

    hipMemsetAsync(d_ws, 0, ((size_t)BH * MM * DD + (size_t)BH * MM) * sizeof(float), stream);
    hipLaunchKernelGGL(kv_kernel, dim3(BH * NCHUNK), dim3(256), 0, stream, k, v, Pm, kvw, ksw);
    hipLaunchKernelGGL(out_kernel, dim3(BH * NCHUNK), dim3(256), 0, stream, q, Pm, kvw, ksw, (float*)d_out);
}